// Round 2
// baseline (347.520 us; speedup 1.0000x reference)
//
#include <hip/hip_runtime.h>
#include <math.h>

#define B_    32
#define C_    256
#define HF    64
#define WF    64
#define M_    4096   // HF*WF
#define N_    128
#define IMGM1 1023.0f
#define TEMP_ 0.1f
#define EPS_  1e-12f
#define NCH   32     // m-chunks in k2 = M_/128
#define SAS   40     // LDS row stride (shorts) for sA/sB: 80 B -> 2-way bank alias only

typedef __attribute__((ext_vector_type(8))) short short8;
typedef __attribute__((ext_vector_type(4))) float floatx4;

__device__ __forceinline__ unsigned short f2bf(float x) {  // RNE fp32->bf16
  unsigned int u = __float_as_uint(x);
  u += 0x7fffu + ((u >> 16) & 1u);
  return (unsigned short)(u >> 16);
}
__device__ __forceinline__ float bf2f(unsigned short h) {
  return __uint_as_float(((unsigned int)h) << 16);
}
__device__ __forceinline__ float wave_sum(float v) {
#pragma unroll
  for (int off = 32; off; off >>= 1) v += __shfl_down(v, off, 64);
  return v;
}

__device__ __forceinline__ void src_geom(float kx, float ky, int& x0, int& y0,
                                         int& x1, int& y1, float& fx, float& fy) {
  const float x = kx / IMGM1 * (float)(WF - 1);
  const float y = ky / IMGM1 * (float)(HF - 1);
  x0 = (int)fminf(fmaxf(floorf(x), 0.f), 63.f);
  y0 = (int)fminf(fmaxf(floorf(y), 0.f), 63.f);
  x1 = min(x0 + 1, 63);
  y1 = min(y0 + 1, 63);
  fx = x - (float)x0;
  fy = y - (float)y0;
}

// ============ k1a: coalesced plane staging -> corner gather (bf16) + ssq atomics ============
// grid (C_/2, B_), block 256. Reads feats_src exactly once, coalesced.
__global__ __launch_bounds__(256) void k1a_stage(const float* __restrict__ fs,
                                                 const float* __restrict__ kps,
                                                 ushort* __restrict__ corner,
                                                 float* __restrict__ ssqg) {
  const int cg = blockIdx.x, b = blockIdx.y, t = threadIdx.x;
  const int c0 = cg * 2;
  __shared__ __align__(16) float plane[2 * M_];   // 32 KB: 2 channel planes
  __shared__ float4 ssq2[256];

  const float4* src = (const float4*)(fs + ((size_t)(b * C_ + c0)) * M_);
  float4* dst = (float4*)plane;
#pragma unroll
  for (int i = 0; i < 8; i++) dst[t + 256 * i] = src[t + 256 * i];
  __syncthreads();

  const int n = t & 127, p = t >> 7;
  const int c = c0 + p;
  const float kx = kps[((size_t)b * N_ + n) * 2 + 0];
  const float ky = kps[((size_t)b * N_ + n) * 2 + 1];
  int x0, y0, x1, y1; float fx, fy;
  src_geom(kx, ky, x0, y0, x1, y1, fx, fy);

  const float* pl = plane + p * M_;
  const float f00 = pl[y0 * WF + x0];
  const float f10 = pl[y1 * WF + x0];
  const float f01 = pl[y0 * WF + x1];
  const float f11 = pl[y1 * WF + x1];

  // coalesced bf16 corner store: corner[b][c][n][4]
  ushort4 cr;
  cr.x = f2bf(f00); cr.y = f2bf(f10); cr.z = f2bf(f01); cr.w = f2bf(f11);
  *(ushort4*)&corner[(((size_t)b * C_ + c) * N_ + n) * 4] = cr;

  ssq2[t] = make_float4(f00 * f00, f10 * f10, f01 * f01, f11 * f11);
  __syncthreads();
  if (t < 128) {
    const float4 a = ssq2[t], bq = ssq2[t + 128];
    float* g = ssqg + ((size_t)b * N_ + t) * 4;
    atomicAdd(g + 0, a.x + bq.x);
    atomicAdd(g + 1, a.y + bq.y);
    atomicAdd(g + 2, a.z + bq.z);
    atomicAdd(g + 3, a.w + bq.w);
  }
}

// ============ k1b2: coalesced tiled normalize+blend -> q (bf16, [b][n][c]) ============
// grid (C_/32, B_), block 256. Reads corner along its fast axis (n), LDS-transposes,
// writes qbf coalesced along c.
__global__ __launch_bounds__(256) void k1b2_combine(const ushort* __restrict__ corner,
                                                    const float* __restrict__ ssqg,
                                                    const float* __restrict__ kps,
                                                    ushort* __restrict__ qbf) {
  const int cg = blockIdx.x, b = blockIdx.y, t = threadIdx.x;
  __shared__ float4 uw[128];
  __shared__ ushort sQ[32][137];   // pad 137: transposed readback ~conflict-free

  if (t < 128) {
    const int n = t;
    const float kx = kps[((size_t)b * N_ + n) * 2 + 0];
    const float ky = kps[((size_t)b * N_ + n) * 2 + 1];
    int x0, y0, x1, y1; float fx, fy;
    src_geom(kx, ky, x0, y0, x1, y1, fx, fy);
    const float wa = (1.f - fx) * (1.f - fy), wb = (1.f - fx) * fy;
    const float wc = fx * (1.f - fy), wd = fx * fy;
    const float4 sq = *(const float4*)&ssqg[((size_t)b * N_ + n) * 4];
    const float r0 = 1.f / fmaxf(sqrtf(sq.x), EPS_);
    const float r1 = 1.f / fmaxf(sqrtf(sq.y), EPS_);
    const float r2 = 1.f / fmaxf(sqrtf(sq.z), EPS_);
    const float r3 = 1.f / fmaxf(sqrtf(sq.w), EPS_);
    uw[n] = make_float4(wa * r0, wb * r1, wc * r2, wd * r3);
  }
  __syncthreads();

  // Phase 1: coalesced corner reads (n fastest) -> combine -> sQ[c_local][n]
  const ushort* cb = corner + (((size_t)b * C_ + cg * 32) * N_) * 4;
#pragma unroll
  for (int i = 0; i < 16; i++) {
    const int e = t + 256 * i;          // 4096 elements = 32c x 128n
    const int n = e & 127, cl = e >> 7;
    const ushort4 cr = *(const ushort4*)&cb[((size_t)cl * N_ + n) * 4];
    const float4 u = uw[n];
    const float qv = u.x * bf2f(cr.x) + u.y * bf2f(cr.y) +
                     u.z * bf2f(cr.z) + u.w * bf2f(cr.w);
    sQ[cl][n] = f2bf(qv);
  }
  __syncthreads();

  // Phase 2: transposed readback, coalesced ushort4 stores along c
  ushort* qb = qbf + (size_t)b * N_ * C_ + cg * 32;
#pragma unroll
  for (int i = 0; i < 4; i++) {
    const int o = t + 256 * i;          // 1024 ushort4 stores = 128n x 8 c-quads
    const int n = o >> 3, c4 = (o & 7) * 4;
    ushort4 w4;
    w4.x = sQ[c4 + 0][n]; w4.y = sQ[c4 + 1][n];
    w4.z = sQ[c4 + 2][n]; w4.w = sQ[c4 + 3][n];
    *(ushort4*)&qb[(size_t)n * C_ + c4] = w4;
  }
}

// ============ k2: bf16 MFMA logits + trg norms + online softmax partials + target logits ============
// grid (NCH, B_), block 256 (4 waves, each a 64x64 output region of the 128n x 128m tile)
// Round-2 changes:
//  - register-prefetch software pipeline: next K-step's global loads issued right after
//    current step's LDS stores -> load latency hides under barrier+ds_read+MFMA+barrier
//  - B staging column assignment m4/{+64} (4-row lane stride): LDS write banks become
//    exactly 2-way (free) instead of structural 4-way (was 3.2M conflict cycles)
__global__ __launch_bounds__(256, 4) void k2_mfma(const float* __restrict__ trg,
                                                  const ushort* __restrict__ qbf,
                                                  const float* __restrict__ kps_trg,
                                                  const int* __restrict__ mask,
                                                  float2* __restrict__ part,
                                                  float* __restrict__ tacc) {
  const int t = threadIdx.x;
  const int mb = blockIdx.x, b = blockIdx.y;
  const int m0 = mb * 128;
  const int wave = t >> 6, lane = t & 63;
  const int wn = wave >> 1, wm = wave & 1;
  const int lg = lane >> 4, ln = lane & 15;

  __shared__ __align__(16) short sA[128 * SAS];      // q tile   [n][k], padded
  __shared__ __align__(16) short sB[128 * SAS];      // trg^T    [m][k], padded + 16B XOR swizzle
  __shared__ __align__(16) float ssqp[16 * 128];
  __shared__ float scl[128];
  __shared__ float2 lser[128 * 2];
  __shared__ __align__(16) int   tidx[128][4];
  __shared__ __align__(16) float tw[128][4];
  __shared__ unsigned tmask[128];                    // per-row bitmask of m-chunks with targets

  floatx4 acc[4][4];
#pragma unroll
  for (int i = 0; i < 4; i++)
#pragma unroll
    for (int j = 0; j < 4; j++) acc[i][j] = (floatx4)0.f;

  float ssq[8];
#pragma unroll
  for (int e = 0; e < 8; e++) ssq[e] = 0.f;

  const ushort* qb = qbf + (size_t)b * N_ * C_;
  const float*  tb = trg + (size_t)b * C_ * M_ + m0;
  const int kk  = 2 * (t >> 4);       // k-pair row for B staging
  const int m4  = (t & 15) * 4;       // first 4-column group for B staging
  const int gB  = kk >> 3;            // 16B chunk containing this k-pair
  const int kin = kk & 7;

  // persistent addressing for the pipelined staging
  const ushort* qA0 = qb + (t >> 2) * C_ + (t & 3) * 8;
  const ushort* qA1 = qA0 + 64 * C_;                    // flat t+256 -> row +64, same chunk
  const int aoff = (t >> 2) * SAS + (t & 3) * 8;        // sA store offsets
  const float* tbase = tb + (size_t)kk * M_ + m4;

  short8 rA0, rA1;
  float4 rBa0, rBa1, rBb0, rBb1;

  // prologue: load tile k0=0
  rA0 = *(const short8*)(qA0);
  rA1 = *(const short8*)(qA1);
  {
    const float* p0 = tbase;
    const float* p1 = p0 + M_;
    rBa0 = *(const float4*)p0;  rBa1 = *(const float4*)(p0 + 64);
    rBb0 = *(const float4*)p1;  rBb1 = *(const float4*)(p1 + 64);
  }

  for (int k0 = 0; k0 < C_; k0 += 32) {
    // --- A store: 128x32 bf16, contiguous 16B stores ---
    *(short8*)&sA[aoff] = rA0;
    *(short8*)&sA[aoff + 64 * SAS] = rA1;
    // --- B convert + store: [m][k] bf16 pairs, XOR-swizzled chunks, 2-way banks ---
    {
      const float v0[8] = {rBa0.x, rBa0.y, rBa0.z, rBa0.w, rBa1.x, rBa1.y, rBa1.z, rBa1.w};
      const float v1[8] = {rBb0.x, rBb0.y, rBb0.z, rBb0.w, rBb1.x, rBb1.y, rBb1.z, rBb1.w};
#pragma unroll
      for (int e = 0; e < 8; e++) {
        ssq[e] += v0[e] * v0[e] + v1[e] * v1[e];
        const int m = m4 + (e & 3) + ((e >> 2) << 6);   // m4+e' or m4+64+e'
        const int fm = (m >> 3) & 3;
        const unsigned int pr = (unsigned int)f2bf(v0[e]) | ((unsigned int)f2bf(v1[e]) << 16);
        *(unsigned int*)&sB[m * SAS + ((gB ^ fm) << 3) + kin] = pr;
      }
    }
    // --- prefetch next K-step into registers (in flight across both barriers + MFMA) ---
    {
      const int kn = k0 + 32;
      if (kn < C_) {
        rA0 = *(const short8*)(qA0 + kn);
        rA1 = *(const short8*)(qA1 + kn);
        const float* p0 = tbase + (size_t)kn * M_;
        const float* p1 = p0 + M_;
        rBa0 = *(const float4*)p0;  rBa1 = *(const float4*)(p0 + 64);
        rBb0 = *(const float4*)p1;  rBb1 = *(const float4*)(p1 + 64);
      }
    }
    __syncthreads();
    short8 af[4], bfr[4];
#pragma unroll
    for (int i = 0; i < 4; i++)
      af[i] = *(const short8*)&sA[(wn * 64 + i * 16 + ln) * SAS + (lg << 3)];
#pragma unroll
    for (int j = 0; j < 4; j++) {
      const int m = wm * 64 + j * 16 + ln;
      const int fm = (m >> 3) & 3;
      bfr[j] = *(const short8*)&sB[m * SAS + ((lg ^ fm) << 3)];
    }
#pragma unroll
    for (int i = 0; i < 4; i++)
#pragma unroll
      for (int j = 0; j < 4; j++)
        acc[i][j] = __builtin_amdgcn_mfma_f32_16x16x32_bf16(af[i], bfr[j], acc[i][j], 0, 0, 0);
    __syncthreads();
  }

  // --- column norms -> scale ---
  *(float4*)&ssqp[(t >> 4) * 128 + m4]      = make_float4(ssq[0], ssq[1], ssq[2], ssq[3]);
  *(float4*)&ssqp[(t >> 4) * 128 + m4 + 64] = make_float4(ssq[4], ssq[5], ssq[6], ssq[7]);
  __syncthreads();
  if (t < 128) {
    float s = 0.f;
#pragma unroll
    for (int g = 0; g < 16; g++) s += ssqp[g * 128 + t];
    scl[t] = 1.f / (fmaxf(sqrtf(s), EPS_) * TEMP_);
    // target keypoint geometry for n = t
    const float kx = kps_trg[((size_t)b * N_ + t) * 2 + 0];
    const float ky = kps_trg[((size_t)b * N_ + t) * 2 + 1];
    const float gx = kx * (1.f / 16.f), gy = ky * (1.f / 16.f);
    const int x0 = (int)fminf(fmaxf(floorf(gx), 0.f), 63.f);
    const int y0 = (int)fminf(fmaxf(floorf(gy), 0.f), 63.f);
    const int x1 = min(x0 + 1, 63), y1 = min(y0 + 1, 63);
    const float x0f = (float)x0, x1f = (float)x1, y0f = (float)y0, y1f = (float)y1;
    const float mk = (mask[(size_t)b * N_ + t] != 0) ? 1.f : 0.f;
    const int i0 = y0 * WF + x0, i1 = y1 * WF + x0;
    const int i2 = y0 * WF + x1, i3 = y1 * WF + x1;
    const float w0 = (x1f - gx) * (y1f - gy) * mk;
    const float w1 = (x1f - gx) * (gy - y0f) * mk;
    const float w2 = (gx - x0f) * (y1f - gy) * mk;
    const float w3 = (gx - x0f) * (gy - y0f) * mk;
    tidx[t][0] = i0; tw[t][0] = w0;
    tidx[t][1] = i1; tw[t][1] = w1;
    tidx[t][2] = i2; tw[t][2] = w2;
    tidx[t][3] = i3; tw[t][3] = w3;
    unsigned tm = 0u;
    if (w0 != 0.f) tm |= 1u << (i0 >> 7);
    if (w1 != 0.f) tm |= 1u << (i1 >> 7);
    if (w2 != 0.f) tm |= 1u << (i2 >> 7);
    if (w3 != 0.f) tm |= 1u << (i3 >> 7);
    tmask[t] = tm;
  }
  __syncthreads();

  float scj[4];
#pragma unroll
  for (int j = 0; j < 4; j++) scj[j] = scl[wm * 64 + j * 16 + ln];
#pragma unroll
  for (int i = 0; i < 4; i++)
#pragma unroll
    for (int j = 0; j < 4; j++) acc[i][j] *= scj[j];

  // --- per-row (max, sumexp) over this wave's 64 m, then target-logit extraction ---
  const unsigned mbbit = 1u << mb;
#pragma unroll
  for (int i = 0; i < 4; i++) {
#pragma unroll
    for (int r = 0; r < 4; r++) {
      float mx = fmaxf(fmaxf(acc[i][0][r], acc[i][1][r]), fmaxf(acc[i][2][r], acc[i][3][r]));
#pragma unroll
      for (int msk = 1; msk < 16; msk <<= 1) mx = fmaxf(mx, __shfl_xor(mx, msk, 64));
      float sm = __expf(acc[i][0][r] - mx) + __expf(acc[i][1][r] - mx) +
                 __expf(acc[i][2][r] - mx) + __expf(acc[i][3][r] - mx);
#pragma unroll
      for (int msk = 1; msk < 16; msk <<= 1) sm += __shfl_xor(sm, msk, 64);
      if (ln == 0) lser[(wn * 64 + i * 16 + lg * 4 + r) * 2 + wm] = make_float2(mx, sm);

      const int n = wn * 64 + i * 16 + lg * 4 + r;
      if (tmask[n] & mbbit) {           // skip dead compare loops: targets rarely in this chunk
        const int4  id4 = *(const int4*)&tidx[n][0];
        const float4 w4 = *(const float4*)&tw[n][0];
        const int   ida[4] = {id4.x, id4.y, id4.z, id4.w};
        const float wwa[4] = {w4.x, w4.y, w4.z, w4.w};
#pragma unroll
        for (int j = 0; j < 4; j++) {
          const int mg = m0 + wm * 64 + j * 16 + ln;
          const float lv = acc[i][j][r];
#pragma unroll
          for (int cc = 0; cc < 4; cc++)
            if (ida[cc] == mg && wwa[cc] != 0.f)
              atomicAdd(&tacc[(size_t)b * N_ + n], wwa[cc] * lv);
        }
      }
    }
  }
  __syncthreads();
  if (t < 128) {
    const float2 u = lser[t * 2 + 0], v = lser[t * 2 + 1];
    const float M = fmaxf(u.x, v.x);
    const float S = u.y * __expf(u.x - M) + v.y * __expf(v.x - M);
    part[((size_t)b * N_ + t) * NCH + mb] = make_float2(M, S);
  }
}

// ============ k4: per-(b,n) loss combine + masked-sum atomics ============
__global__ __launch_bounds__(128) void k4_comb(const float2* __restrict__ part,
                                               const float* __restrict__ tacc,
                                               const float* __restrict__ kps_trg,
                                               const int* __restrict__ mask,
                                               float* __restrict__ gs) {
  const int b = blockIdx.x, t = threadIdx.x;  // t = n
  const float2* p = part + ((size_t)b * N_ + t) * NCH;
  float M = -INFINITY;
#pragma unroll 8
  for (int c = 0; c < NCH; c++) M = fmaxf(M, p[c].x);
  float S = 0.f;
#pragma unroll 8
  for (int c = 0; c < NCH; c++) S += p[c].y * __expf(p[c].x - M);
  const float lse = M + logf(S);

  const float kx = kps_trg[((size_t)b * N_ + t) * 2 + 0];
  const float ky = kps_trg[((size_t)b * N_ + t) * 2 + 1];
  const float gx = kx * (1.f / 16.f), gy = ky * (1.f / 16.f);
  const int x0 = (int)fminf(fmaxf(floorf(gx), 0.f), 63.f);
  const int y0 = (int)fminf(fmaxf(floorf(gy), 0.f), 63.f);
  const int x1 = min(x0 + 1, 63), y1 = min(y0 + 1, 63);
  const float mk = (mask[(size_t)b * N_ + t] != 0) ? 1.f : 0.f;
  const float wsum = (float)(x1 - x0) * (float)(y1 - y0) * mk;

  float loss = wsum * lse - tacc[(size_t)b * N_ + t];
  float cnt = mk;
  loss = wave_sum(loss);
  cnt = wave_sum(cnt);
  __shared__ float sl[2], sc2[2];
  if ((t & 63) == 0) { sl[t >> 6] = loss; sc2[t >> 6] = cnt; }
  __syncthreads();
  if (t == 0) {
    atomicAdd(&gs[0], sl[0] + sl[1]);
    atomicAdd(&gs[1], sc2[0] + sc2[1]);
  }
}

__global__ void k5_final(const float* __restrict__ gs, float* __restrict__ out) {
  out[0] = gs[0] / fmaxf(gs[1], 1.f);
}

extern "C" void kernel_launch(void* const* d_in, const int* in_sizes, int n_in,
                              void* d_out, int out_size, void* d_ws, size_t ws_size,
                              hipStream_t stream) {
  const float* feats_src = (const float*)d_in[0];
  const float* feats_trg = (const float*)d_in[1];
  const float* kps_src   = (const float*)d_in[2];
  const float* kps_trg   = (const float*)d_in[3];
  const int*   kps_mask  = (const int*)d_in[4];
  float* out = (float*)d_out;

  // ws layout (bytes):
  //   0            ssqg   : B*N*4 floats          = 65536
  //   65536        tacc   : B*N floats            = 16384
  //   81920        gs     : 2 floats              = 8
  //   82432        corner : B*C*N*4 ushort        = 8388608
  //   8471040      qbf    : B*N*C ushort          = 2097152
  //   10568192     part   : B*N*NCH float2        = 1048576
  //   total ~11.6 MB
  char* wsb = (char*)d_ws;
  float*  ssqg   = (float*)(wsb + 0);
  float*  tacc   = (float*)(wsb + 65536);
  float*  gs     = (float*)(wsb + 81920);
  ushort* corner = (ushort*)(wsb + 82432);
  ushort* qbf    = (ushort*)(wsb + 8471040);
  float2* part   = (float2*)(wsb + 10568192);

  hipMemsetAsync(wsb, 0, 81928, stream);  // zero ssqg + tacc + gs

  k1a_stage<<<dim3(C_ / 2, B_), 256, 0, stream>>>(feats_src, kps_src, corner, ssqg);
  k1b2_combine<<<dim3(C_ / 32, B_), 256, 0, stream>>>(corner, ssqg, kps_src, qbf);
  k2_mfma<<<dim3(NCH, B_), 256, 0, stream>>>(feats_trg, qbf, kps_trg, kps_mask, part, tacc);
  k4_comb<<<dim3(B_), 128, 0, stream>>>(part, tacc, kps_trg, kps_mask, gs);
  k5_final<<<1, 1, 0, stream>>>(gs, out);
}

// Round 3
// 337.854 us; speedup vs baseline: 1.0286x; 1.0286x over previous
//
#include <hip/hip_runtime.h>
#include <math.h>

#define B_    32
#define C_    256
#define HF    64
#define WF    64
#define M_    4096   // HF*WF
#define N_    128
#define IMGM1 1023.0f
#define TEMP_ 0.1f
#define EPS_  1e-12f
#define NCH   64     // m-chunks in k2 = M_/64
#define MT    64     // k2 m-tile
#define SAS   40     // LDS row stride (shorts) for sA/sB: 80 B -> 2-way bank alias only

typedef __attribute__((ext_vector_type(8))) short short8;
typedef __attribute__((ext_vector_type(4))) float floatx4;

__device__ __forceinline__ unsigned short f2bf(float x) {  // RNE fp32->bf16
  unsigned int u = __float_as_uint(x);
  u += 0x7fffu + ((u >> 16) & 1u);
  return (unsigned short)(u >> 16);
}
__device__ __forceinline__ float bf2f(unsigned short h) {
  return __uint_as_float(((unsigned int)h) << 16);
}
__device__ __forceinline__ float wave_sum(float v) {
#pragma unroll
  for (int off = 32; off; off >>= 1) v += __shfl_down(v, off, 64);
  return v;
}

__device__ __forceinline__ void src_geom(float kx, float ky, int& x0, int& y0,
                                         int& x1, int& y1, float& fx, float& fy) {
  const float x = kx / IMGM1 * (float)(WF - 1);
  const float y = ky / IMGM1 * (float)(HF - 1);
  x0 = (int)fminf(fmaxf(floorf(x), 0.f), 63.f);
  y0 = (int)fminf(fmaxf(floorf(y), 0.f), 63.f);
  x1 = min(x0 + 1, 63);
  y1 = min(y0 + 1, 63);
  fx = x - (float)x0;
  fy = y - (float)y0;
}

// ============ k1a: coalesced plane staging -> corner gather (bf16) + ssq atomics ============
// grid (C_/2, B_), block 256. Reads feats_src exactly once, coalesced.
__global__ __launch_bounds__(256) void k1a_stage(const float* __restrict__ fs,
                                                 const float* __restrict__ kps,
                                                 ushort* __restrict__ corner,
                                                 float* __restrict__ ssqg) {
  const int cg = blockIdx.x, b = blockIdx.y, t = threadIdx.x;
  const int c0 = cg * 2;
  __shared__ __align__(16) float plane[2 * M_];   // 32 KB: 2 channel planes
  __shared__ float4 ssq2[256];

  const float4* src = (const float4*)(fs + ((size_t)(b * C_ + c0)) * M_);
  float4* dst = (float4*)plane;
#pragma unroll
  for (int i = 0; i < 8; i++) dst[t + 256 * i] = src[t + 256 * i];
  __syncthreads();

  const int n = t & 127, p = t >> 7;
  const int c = c0 + p;
  const float kx = kps[((size_t)b * N_ + n) * 2 + 0];
  const float ky = kps[((size_t)b * N_ + n) * 2 + 1];
  int x0, y0, x1, y1; float fx, fy;
  src_geom(kx, ky, x0, y0, x1, y1, fx, fy);

  const float* pl = plane + p * M_;
  const float f00 = pl[y0 * WF + x0];
  const float f10 = pl[y1 * WF + x0];
  const float f01 = pl[y0 * WF + x1];
  const float f11 = pl[y1 * WF + x1];

  // coalesced bf16 corner store: corner[b][c][n][4]
  ushort4 cr;
  cr.x = f2bf(f00); cr.y = f2bf(f10); cr.z = f2bf(f01); cr.w = f2bf(f11);
  *(ushort4*)&corner[(((size_t)b * C_ + c) * N_ + n) * 4] = cr;

  ssq2[t] = make_float4(f00 * f00, f10 * f10, f01 * f01, f11 * f11);
  __syncthreads();
  if (t < 128) {
    const float4 a = ssq2[t], bq = ssq2[t + 128];
    float* g = ssqg + ((size_t)b * N_ + t) * 4;
    atomicAdd(g + 0, a.x + bq.x);
    atomicAdd(g + 1, a.y + bq.y);
    atomicAdd(g + 2, a.z + bq.z);
    atomicAdd(g + 3, a.w + bq.w);
  }
}

// ============ k1b2: coalesced tiled normalize+blend -> q (bf16, [b][n][c]) ============
// grid (C_/32, B_), block 256. Reads corner along its fast axis (n), LDS-transposes,
// writes qbf coalesced along c.
__global__ __launch_bounds__(256) void k1b2_combine(const ushort* __restrict__ corner,
                                                    const float* __restrict__ ssqg,
                                                    const float* __restrict__ kps,
                                                    ushort* __restrict__ qbf) {
  const int cg = blockIdx.x, b = blockIdx.y, t = threadIdx.x;
  __shared__ float4 uw[128];
  __shared__ ushort sQ[32][137];   // pad 137: transposed readback ~conflict-free

  if (t < 128) {
    const int n = t;
    const float kx = kps[((size_t)b * N_ + n) * 2 + 0];
    const float ky = kps[((size_t)b * N_ + n) * 2 + 1];
    int x0, y0, x1, y1; float fx, fy;
    src_geom(kx, ky, x0, y0, x1, y1, fx, fy);
    const float wa = (1.f - fx) * (1.f - fy), wb = (1.f - fx) * fy;
    const float wc = fx * (1.f - fy), wd = fx * fy;
    const float4 sq = *(const float4*)&ssqg[((size_t)b * N_ + n) * 4];
    const float r0 = 1.f / fmaxf(sqrtf(sq.x), EPS_);
    const float r1 = 1.f / fmaxf(sqrtf(sq.y), EPS_);
    const float r2 = 1.f / fmaxf(sqrtf(sq.z), EPS_);
    const float r3 = 1.f / fmaxf(sqrtf(sq.w), EPS_);
    uw[n] = make_float4(wa * r0, wb * r1, wc * r2, wd * r3);
  }
  __syncthreads();

  // Phase 1: coalesced corner reads (n fastest) -> combine -> sQ[c_local][n]
  const ushort* cb = corner + (((size_t)b * C_ + cg * 32) * N_) * 4;
#pragma unroll
  for (int i = 0; i < 16; i++) {
    const int e = t + 256 * i;          // 4096 elements = 32c x 128n
    const int n = e & 127, cl = e >> 7;
    const ushort4 cr = *(const ushort4*)&cb[((size_t)cl * N_ + n) * 4];
    const float4 u = uw[n];
    const float qv = u.x * bf2f(cr.x) + u.y * bf2f(cr.y) +
                     u.z * bf2f(cr.z) + u.w * bf2f(cr.w);
    sQ[cl][n] = f2bf(qv);
  }
  __syncthreads();

  // Phase 2: transposed readback, coalesced ushort4 stores along c
  ushort* qb = qbf + (size_t)b * N_ * C_ + cg * 32;
#pragma unroll
  for (int i = 0; i < 4; i++) {
    const int o = t + 256 * i;          // 1024 ushort4 stores = 128n x 8 c-quads
    const int n = o >> 3, c4 = (o & 7) * 4;
    ushort4 w4;
    w4.x = sQ[c4 + 0][n]; w4.y = sQ[c4 + 1][n];
    w4.z = sQ[c4 + 2][n]; w4.w = sQ[c4 + 3][n];
    *(ushort4*)&qb[(size_t)n * C_ + c4] = w4;
  }
}

// ============ k2: bf16 MFMA logits + trg norms + online softmax partials + target logits ============
// Round-3 restructure: 128n x 64m tile per block (was 128x128), grid (64, 32) = 2048 blocks.
//  - acc halves to 8 frags (32 VGPR) -> no launch_bounds cap needed, no spill
//  - LDS 26 KB (was 35) -> ~5-6 blocks/CU occupancy (was ~3): desynchronized blocks keep
//    the memory system busy through the barrier phases (k2 was phase-alternation-bound)
//  - register prefetch of next K-step retained (spill-free now)
//  - B-staging 2-way LDS write banks retained
__global__ __launch_bounds__(256) void k2_mfma(const float* __restrict__ trg,
                                               const ushort* __restrict__ qbf,
                                               const float* __restrict__ kps_trg,
                                               const int* __restrict__ mask,
                                               float2* __restrict__ part,
                                               float* __restrict__ tacc) {
  const int t = threadIdx.x;
  const int mb = blockIdx.x, b = blockIdx.y;
  const int m0 = mb * MT;
  const int wave = t >> 6, lane = t & 63;
  const int wn2 = wave >> 1, wm2 = wave & 1;   // n-half, m-half
  const int lg = lane >> 4, ln = lane & 15;

  __shared__ __align__(16) short sA[128 * SAS];      // q tile   [n][k], padded
  __shared__ __align__(16) short sB[MT * SAS];       // trg^T    [m][k], padded + XOR swizzle
  __shared__ __align__(16) float ssqp[16 * MT];
  __shared__ float scl[MT];
  __shared__ float2 lser[N_ * 2];
  __shared__ __align__(16) int   tidx[N_][4];
  __shared__ __align__(16) float tw[N_][4];
  __shared__ unsigned long long tmask[N_];           // per-row bitmask of 64 m-chunks

  floatx4 acc[4][2];
#pragma unroll
  for (int i = 0; i < 4; i++)
#pragma unroll
    for (int j = 0; j < 2; j++) acc[i][j] = (floatx4)0.f;

  float ssq[4] = {0.f, 0.f, 0.f, 0.f};

  const ushort* qb = qbf + (size_t)b * N_ * C_;
  const float*  tb = trg + (size_t)b * C_ * M_ + m0;
  const int kk  = 2 * (t >> 4);       // k-pair row for B staging (16 groups x 2 rows = 32 k)
  const int m4  = (t & 15) * 4;       // 4-column group for B staging (16 x 4 = 64 m)
  const int gB  = kk >> 3;            // 16B chunk containing this k-pair
  const int kin = kk & 7;

  // persistent addressing for the pipelined staging
  const ushort* qA0 = qb + (t >> 2) * C_ + (t & 3) * 8;
  const ushort* qA1 = qA0 + 64 * C_;
  const int aoff = (t >> 2) * SAS + (t & 3) * 8;
  const float* tbase = tb + (size_t)kk * M_ + m4;

  short8 rA0, rA1;
  float4 rB0, rB1;

  // prologue: load tile k0=0
  rA0 = *(const short8*)(qA0);
  rA1 = *(const short8*)(qA1);
  rB0 = *(const float4*)(tbase);
  rB1 = *(const float4*)(tbase + M_);

  for (int k0 = 0; k0 < C_; k0 += 32) {
    // --- A store: 128x32 bf16, contiguous 16B stores ---
    *(short8*)&sA[aoff] = rA0;
    *(short8*)&sA[aoff + 64 * SAS] = rA1;
    // --- B convert + store: [m][k] bf16 pairs, XOR-swizzled chunks, 2-way banks ---
    {
      const float v0[4] = {rB0.x, rB0.y, rB0.z, rB0.w};
      const float v1[4] = {rB1.x, rB1.y, rB1.z, rB1.w};
#pragma unroll
      for (int e = 0; e < 4; e++) {
        ssq[e] += v0[e] * v0[e] + v1[e] * v1[e];
        const int m = m4 + e;
        const int fm = (m >> 3) & 3;
        const unsigned int pr = (unsigned int)f2bf(v0[e]) | ((unsigned int)f2bf(v1[e]) << 16);
        *(unsigned int*)&sB[m * SAS + ((gB ^ fm) << 3) + kin] = pr;
      }
    }
    // --- prefetch next K-step into registers (in flight across barriers + MFMA) ---
    {
      const int kn = k0 + 32;
      if (kn < C_) {
        rA0 = *(const short8*)(qA0 + kn);
        rA1 = *(const short8*)(qA1 + kn);
        rB0 = *(const float4*)(tbase + (size_t)kn * M_);
        rB1 = *(const float4*)(tbase + (size_t)kn * M_ + M_);
      }
    }
    __syncthreads();
    short8 af[4], bfr[2];
#pragma unroll
    for (int i = 0; i < 4; i++)
      af[i] = *(const short8*)&sA[(wn2 * 64 + i * 16 + ln) * SAS + (lg << 3)];
#pragma unroll
    for (int j = 0; j < 2; j++) {
      const int m = wm2 * 32 + j * 16 + ln;
      const int fm = (m >> 3) & 3;
      bfr[j] = *(const short8*)&sB[m * SAS + ((lg ^ fm) << 3)];
    }
#pragma unroll
    for (int i = 0; i < 4; i++)
#pragma unroll
      for (int j = 0; j < 2; j++)
        acc[i][j] = __builtin_amdgcn_mfma_f32_16x16x32_bf16(af[i], bfr[j], acc[i][j], 0, 0, 0);
    __syncthreads();
  }

  // --- column norms -> scale ---
  *(float4*)&ssqp[(t >> 4) * MT + m4] = make_float4(ssq[0], ssq[1], ssq[2], ssq[3]);
  __syncthreads();
  if (t < MT) {
    float s = 0.f;
#pragma unroll
    for (int g = 0; g < 16; g++) s += ssqp[g * MT + t];
    scl[t] = 1.f / (fmaxf(sqrtf(s), EPS_) * TEMP_);
  }
  if (t < 128) {
    // target keypoint geometry for n = t
    const float kx = kps_trg[((size_t)b * N_ + t) * 2 + 0];
    const float ky = kps_trg[((size_t)b * N_ + t) * 2 + 1];
    const float gx = kx * (1.f / 16.f), gy = ky * (1.f / 16.f);
    const int x0 = (int)fminf(fmaxf(floorf(gx), 0.f), 63.f);
    const int y0 = (int)fminf(fmaxf(floorf(gy), 0.f), 63.f);
    const int x1 = min(x0 + 1, 63), y1 = min(y0 + 1, 63);
    const float x0f = (float)x0, x1f = (float)x1, y0f = (float)y0, y1f = (float)y1;
    const float mk = (mask[(size_t)b * N_ + t] != 0) ? 1.f : 0.f;
    const int i0 = y0 * WF + x0, i1 = y1 * WF + x0;
    const int i2 = y0 * WF + x1, i3 = y1 * WF + x1;
    const float w0 = (x1f - gx) * (y1f - gy) * mk;
    const float w1 = (x1f - gx) * (gy - y0f) * mk;
    const float w2 = (gx - x0f) * (y1f - gy) * mk;
    const float w3 = (gx - x0f) * (gy - y0f) * mk;
    tidx[t][0] = i0; tw[t][0] = w0;
    tidx[t][1] = i1; tw[t][1] = w1;
    tidx[t][2] = i2; tw[t][2] = w2;
    tidx[t][3] = i3; tw[t][3] = w3;
    unsigned long long tm = 0ull;
    if (w0 != 0.f) tm |= 1ull << (i0 >> 6);
    if (w1 != 0.f) tm |= 1ull << (i1 >> 6);
    if (w2 != 0.f) tm |= 1ull << (i2 >> 6);
    if (w3 != 0.f) tm |= 1ull << (i3 >> 6);
    tmask[t] = tm;
  }
  __syncthreads();

  float scj[2];
#pragma unroll
  for (int j = 0; j < 2; j++) scj[j] = scl[wm2 * 32 + j * 16 + ln];
#pragma unroll
  for (int i = 0; i < 4; i++)
#pragma unroll
    for (int j = 0; j < 2; j++) acc[i][j] *= scj[j];

  // --- per-row (max, sumexp) over this wave's 32 m, then target-logit extraction ---
  const unsigned long long mbbit = 1ull << mb;
#pragma unroll
  for (int i = 0; i < 4; i++) {
#pragma unroll
    for (int r = 0; r < 4; r++) {
      float mx = fmaxf(acc[i][0][r], acc[i][1][r]);
#pragma unroll
      for (int msk = 1; msk < 16; msk <<= 1) mx = fmaxf(mx, __shfl_xor(mx, msk, 64));
      float sm = __expf(acc[i][0][r] - mx) + __expf(acc[i][1][r] - mx);
#pragma unroll
      for (int msk = 1; msk < 16; msk <<= 1) sm += __shfl_xor(sm, msk, 64);
      const int n = wn2 * 64 + i * 16 + lg * 4 + r;
      if (ln == 0) lser[n * 2 + wm2] = make_float2(mx, sm);

      if (tmask[n] & mbbit) {           // skip dead compare loops: targets rarely in this chunk
        const int4  id4 = *(const int4*)&tidx[n][0];
        const float4 w4 = *(const float4*)&tw[n][0];
        const int   ida[4] = {id4.x, id4.y, id4.z, id4.w};
        const float wwa[4] = {w4.x, w4.y, w4.z, w4.w};
#pragma unroll
        for (int j = 0; j < 2; j++) {
          const int mg = m0 + wm2 * 32 + j * 16 + ln;
          const float lv = acc[i][j][r];
#pragma unroll
          for (int cc = 0; cc < 4; cc++)
            if (ida[cc] == mg && wwa[cc] != 0.f)
              atomicAdd(&tacc[(size_t)b * N_ + n], wwa[cc] * lv);
        }
      }
    }
  }
  __syncthreads();
  if (t < 128) {
    const float2 u = lser[t * 2 + 0], v = lser[t * 2 + 1];
    const float M = fmaxf(u.x, v.x);
    const float S = u.y * __expf(u.x - M) + v.y * __expf(v.x - M);
    // part layout [b][mb][n]: coalesced write here, coalesced read in k4
    part[((size_t)b * NCH + mb) * N_ + t] = make_float2(M, S);
  }
}

// ============ k4: per-(b,n) loss combine + masked-sum atomics ============
__global__ __launch_bounds__(128) void k4_comb(const float2* __restrict__ part,
                                               const float* __restrict__ tacc,
                                               const float* __restrict__ kps_trg,
                                               const int* __restrict__ mask,
                                               float* __restrict__ gs) {
  const int b = blockIdx.x, t = threadIdx.x;  // t = n
  const float2* p = part + (size_t)b * NCH * N_ + t;   // [b][c][n], stride N_ over c
  float M = -INFINITY;
#pragma unroll 8
  for (int c = 0; c < NCH; c++) M = fmaxf(M, p[(size_t)c * N_].x);
  float S = 0.f;
#pragma unroll 8
  for (int c = 0; c < NCH; c++) {
    const float2 v = p[(size_t)c * N_];
    S += v.y * __expf(v.x - M);
  }
  const float lse = M + logf(S);

  const float kx = kps_trg[((size_t)b * N_ + t) * 2 + 0];
  const float ky = kps_trg[((size_t)b * N_ + t) * 2 + 1];
  const float gx = kx * (1.f / 16.f), gy = ky * (1.f / 16.f);
  const int x0 = (int)fminf(fmaxf(floorf(gx), 0.f), 63.f);
  const int y0 = (int)fminf(fmaxf(floorf(gy), 0.f), 63.f);
  const int x1 = min(x0 + 1, 63), y1 = min(y0 + 1, 63);
  const float mk = (mask[(size_t)b * N_ + t] != 0) ? 1.f : 0.f;
  const float wsum = (float)(x1 - x0) * (float)(y1 - y0) * mk;

  float loss = wsum * lse - tacc[(size_t)b * N_ + t];
  float cnt = mk;
  loss = wave_sum(loss);
  cnt = wave_sum(cnt);
  __shared__ float sl[2], sc2[2];
  if ((t & 63) == 0) { sl[t >> 6] = loss; sc2[t >> 6] = cnt; }
  __syncthreads();
  if (t == 0) {
    atomicAdd(&gs[0], sl[0] + sl[1]);
    atomicAdd(&gs[1], sc2[0] + sc2[1]);
  }
}

__global__ void k5_final(const float* __restrict__ gs, float* __restrict__ out) {
  out[0] = gs[0] / fmaxf(gs[1], 1.f);
}

extern "C" void kernel_launch(void* const* d_in, const int* in_sizes, int n_in,
                              void* d_out, int out_size, void* d_ws, size_t ws_size,
                              hipStream_t stream) {
  const float* feats_src = (const float*)d_in[0];
  const float* feats_trg = (const float*)d_in[1];
  const float* kps_src   = (const float*)d_in[2];
  const float* kps_trg   = (const float*)d_in[3];
  const int*   kps_mask  = (const int*)d_in[4];
  float* out = (float*)d_out;

  // ws layout (bytes):
  //   0            ssqg   : B*N*4 floats          = 65536
  //   65536        tacc   : B*N floats            = 16384
  //   81920        gs     : 2 floats              = 8
  //   82432        corner : B*C*N*4 ushort        = 8388608
  //   8471040      qbf    : B*N*C ushort          = 2097152
  //   10568192     part   : B*NCH*N float2        = 2097152
  //   total ~12.7 MB
  char* wsb = (char*)d_ws;
  float*  ssqg   = (float*)(wsb + 0);
  float*  tacc   = (float*)(wsb + 65536);
  float*  gs     = (float*)(wsb + 81920);
  ushort* corner = (ushort*)(wsb + 82432);
  ushort* qbf    = (ushort*)(wsb + 8471040);
  float2* part   = (float2*)(wsb + 10568192);

  hipMemsetAsync(wsb, 0, 81928, stream);  // zero ssqg + tacc + gs

  k1a_stage<<<dim3(C_ / 2, B_), 256, 0, stream>>>(feats_src, kps_src, corner, ssqg);
  k1b2_combine<<<dim3(C_ / 32, B_), 256, 0, stream>>>(corner, ssqg, kps_src, qbf);
  k2_mfma<<<dim3(NCH, B_), 256, 0, stream>>>(feats_trg, qbf, kps_trg, kps_mask, part, tacc);
  k4_comb<<<dim3(B_), 128, 0, stream>>>(part, tacc, kps_trg, kps_mask, gs);
  k5_final<<<1, 1, 0, stream>>>(gs, out);
}

// Round 4
// 326.262 us; speedup vs baseline: 1.0652x; 1.0355x over previous
//
#include <hip/hip_runtime.h>
#include <math.h>

#define B_    32
#define C_    256
#define HF    64
#define WF    64
#define M_    4096   // HF*WF
#define N_    128
#define IMGM1 1023.0f
#define TEMP_ 0.1f
#define EPS_  1e-12f
#define NCH   32     // m-chunks in k2 = M_/128
#define SAS   40     // LDS row stride (shorts) for sA/sB: 80 B -> 2-way bank alias only

typedef __attribute__((ext_vector_type(8))) short short8;
typedef __attribute__((ext_vector_type(4))) float floatx4;

__device__ __forceinline__ unsigned short f2bf(float x) {  // RNE fp32->bf16
  unsigned int u = __float_as_uint(x);
  u += 0x7fffu + ((u >> 16) & 1u);
  return (unsigned short)(u >> 16);
}
__device__ __forceinline__ float bf2f(unsigned short h) {
  return __uint_as_float(((unsigned int)h) << 16);
}
__device__ __forceinline__ float wave_sum(float v) {
#pragma unroll
  for (int off = 32; off; off >>= 1) v += __shfl_down(v, off, 64);
  return v;
}

__device__ __forceinline__ void src_geom(float kx, float ky, int& x0, int& y0,
                                         int& x1, int& y1, float& fx, float& fy) {
  const float x = kx / IMGM1 * (float)(WF - 1);
  const float y = ky / IMGM1 * (float)(HF - 1);
  x0 = (int)fminf(fmaxf(floorf(x), 0.f), 63.f);
  y0 = (int)fminf(fmaxf(floorf(y), 0.f), 63.f);
  x1 = min(x0 + 1, 63);
  y1 = min(y0 + 1, 63);
  fx = x - (float)x0;
  fy = y - (float)y0;
}

// ============ k1a: coalesced plane staging -> corner gather (bf16) + ssq atomics ============
// grid (C_/2, B_), block 256. Reads feats_src exactly once, coalesced.
__global__ __launch_bounds__(256) void k1a_stage(const float* __restrict__ fs,
                                                 const float* __restrict__ kps,
                                                 ushort* __restrict__ corner,
                                                 float* __restrict__ ssqg) {
  const int cg = blockIdx.x, b = blockIdx.y, t = threadIdx.x;
  const int c0 = cg * 2;
  __shared__ __align__(16) float plane[2 * M_];   // 32 KB: 2 channel planes
  __shared__ float4 ssq2[256];

  const float4* src = (const float4*)(fs + ((size_t)(b * C_ + c0)) * M_);
  float4* dst = (float4*)plane;
#pragma unroll
  for (int i = 0; i < 8; i++) dst[t + 256 * i] = src[t + 256 * i];
  __syncthreads();

  const int n = t & 127, p = t >> 7;
  const int c = c0 + p;
  const float kx = kps[((size_t)b * N_ + n) * 2 + 0];
  const float ky = kps[((size_t)b * N_ + n) * 2 + 1];
  int x0, y0, x1, y1; float fx, fy;
  src_geom(kx, ky, x0, y0, x1, y1, fx, fy);

  const float* pl = plane + p * M_;
  const float f00 = pl[y0 * WF + x0];
  const float f10 = pl[y1 * WF + x0];
  const float f01 = pl[y0 * WF + x1];
  const float f11 = pl[y1 * WF + x1];

  // coalesced bf16 corner store: corner[b][c][n][4]
  ushort4 cr;
  cr.x = f2bf(f00); cr.y = f2bf(f10); cr.z = f2bf(f01); cr.w = f2bf(f11);
  *(ushort4*)&corner[(((size_t)b * C_ + c) * N_ + n) * 4] = cr;

  ssq2[t] = make_float4(f00 * f00, f10 * f10, f01 * f01, f11 * f11);
  __syncthreads();
  if (t < 128) {
    const float4 a = ssq2[t], bq = ssq2[t + 128];
    float* g = ssqg + ((size_t)b * N_ + t) * 4;
    atomicAdd(g + 0, a.x + bq.x);
    atomicAdd(g + 1, a.y + bq.y);
    atomicAdd(g + 2, a.z + bq.z);
    atomicAdd(g + 3, a.w + bq.w);
  }
}

// ============ k1b2: coalesced tiled normalize+blend -> q (bf16, [b][n][c]) ============
// grid (C_/32, B_), block 256. Reads corner along its fast axis (n), LDS-transposes,
// writes qbf coalesced along c.
__global__ __launch_bounds__(256) void k1b2_combine(const ushort* __restrict__ corner,
                                                    const float* __restrict__ ssqg,
                                                    const float* __restrict__ kps,
                                                    ushort* __restrict__ qbf) {
  const int cg = blockIdx.x, b = blockIdx.y, t = threadIdx.x;
  __shared__ float4 uw[128];
  __shared__ ushort sQ[32][137];   // pad 137: transposed readback ~conflict-free

  if (t < 128) {
    const int n = t;
    const float kx = kps[((size_t)b * N_ + n) * 2 + 0];
    const float ky = kps[((size_t)b * N_ + n) * 2 + 1];
    int x0, y0, x1, y1; float fx, fy;
    src_geom(kx, ky, x0, y0, x1, y1, fx, fy);
    const float wa = (1.f - fx) * (1.f - fy), wb = (1.f - fx) * fy;
    const float wc = fx * (1.f - fy), wd = fx * fy;
    const float4 sq = *(const float4*)&ssqg[((size_t)b * N_ + n) * 4];
    const float r0 = 1.f / fmaxf(sqrtf(sq.x), EPS_);
    const float r1 = 1.f / fmaxf(sqrtf(sq.y), EPS_);
    const float r2 = 1.f / fmaxf(sqrtf(sq.z), EPS_);
    const float r3 = 1.f / fmaxf(sqrtf(sq.w), EPS_);
    uw[n] = make_float4(wa * r0, wb * r1, wc * r2, wd * r3);
  }
  __syncthreads();

  // Phase 1: coalesced corner reads (n fastest) -> combine -> sQ[c_local][n]
  const ushort* cb = corner + (((size_t)b * C_ + cg * 32) * N_) * 4;
#pragma unroll
  for (int i = 0; i < 16; i++) {
    const int e = t + 256 * i;          // 4096 elements = 32c x 128n
    const int n = e & 127, cl = e >> 7;
    const ushort4 cr = *(const ushort4*)&cb[((size_t)cl * N_ + n) * 4];
    const float4 u = uw[n];
    const float qv = u.x * bf2f(cr.x) + u.y * bf2f(cr.y) +
                     u.z * bf2f(cr.z) + u.w * bf2f(cr.w);
    sQ[cl][n] = f2bf(qv);
  }
  __syncthreads();

  // Phase 2: transposed readback, coalesced ushort4 stores along c
  ushort* qb = qbf + (size_t)b * N_ * C_ + cg * 32;
#pragma unroll
  for (int i = 0; i < 4; i++) {
    const int o = t + 256 * i;          // 1024 ushort4 stores = 128n x 8 c-quads
    const int n = o >> 3, c4 = (o & 7) * 4;
    ushort4 w4;
    w4.x = sQ[c4 + 0][n]; w4.y = sQ[c4 + 1][n];
    w4.z = sQ[c4 + 2][n]; w4.w = sQ[c4 + 3][n];
    *(ushort4*)&qb[(size_t)n * C_ + c4] = w4;
  }
}

// ============ k2: bf16 MFMA logits + trg norms + online softmax partials + target logits ============
// grid (NCH, B_), block 256 (4 waves, each a 64x64 output region of the 128n x 128m tile)
// Round-4: round-1 structure (MT=128, known 81 us) + two independent spill-free tweaks:
//  - register prefetch of next K-step (NO launch_bounds cap -> no scratch spill; round-2's
//    regression was the VGPR=64 cap, not the prefetch itself)
//  - B staging column split m4/{m4+64} (4-row lane stride): write banks 2-way (free)
//    instead of structural 4-way (measured 3.2M -> 2.1M conflicts in round 2)
__global__ __launch_bounds__(256) void k2_mfma(const float* __restrict__ trg,
                                               const ushort* __restrict__ qbf,
                                               const float* __restrict__ kps_trg,
                                               const int* __restrict__ mask,
                                               float2* __restrict__ part,
                                               float* __restrict__ tacc) {
  const int t = threadIdx.x;
  const int mb = blockIdx.x, b = blockIdx.y;
  const int m0 = mb * 128;
  const int wave = t >> 6, lane = t & 63;
  const int wn = wave >> 1, wm = wave & 1;
  const int lg = lane >> 4, ln = lane & 15;

  __shared__ __align__(16) short sA[128 * SAS];      // q tile   [n][k], padded
  __shared__ __align__(16) short sB[128 * SAS];      // trg^T    [m][k], padded + 16B XOR swizzle
  __shared__ __align__(16) float ssqp[16 * 128];
  __shared__ float scl[128];
  __shared__ float2 lser[128 * 2];
  __shared__ __align__(16) int   tidx[128][4];
  __shared__ __align__(16) float tw[128][4];
  __shared__ unsigned tmask[128];                    // per-row bitmask of m-chunks with targets

  floatx4 acc[4][4];
#pragma unroll
  for (int i = 0; i < 4; i++)
#pragma unroll
    for (int j = 0; j < 4; j++) acc[i][j] = (floatx4)0.f;

  float ssq[8];
#pragma unroll
  for (int e = 0; e < 8; e++) ssq[e] = 0.f;

  const ushort* qb = qbf + (size_t)b * N_ * C_;
  const float*  tb = trg + (size_t)b * C_ * M_ + m0;
  const int kk  = 2 * (t >> 4);       // k-pair row for B staging
  const int m4  = (t & 15) * 4;       // first 4-column group for B staging
  const int gB  = kk >> 3;            // 16B chunk containing this k-pair
  const int kin = kk & 7;

  // persistent addressing for the pipelined staging
  const ushort* qA0 = qb + (t >> 2) * C_ + (t & 3) * 8;
  const ushort* qA1 = qA0 + 64 * C_;
  const int aoff = (t >> 2) * SAS + (t & 3) * 8;
  const float* tbase = tb + (size_t)kk * M_ + m4;

  short8 rA0, rA1;
  float4 rBa0, rBa1, rBb0, rBb1;

  // prologue: load tile k0=0
  rA0 = *(const short8*)(qA0);
  rA1 = *(const short8*)(qA1);
  {
    const float* p0 = tbase;
    const float* p1 = p0 + M_;
    rBa0 = *(const float4*)p0;  rBa1 = *(const float4*)(p0 + 64);
    rBb0 = *(const float4*)p1;  rBb1 = *(const float4*)(p1 + 64);
  }

  for (int k0 = 0; k0 < C_; k0 += 32) {
    // --- A store: 128x32 bf16, contiguous 16B stores ---
    *(short8*)&sA[aoff] = rA0;
    *(short8*)&sA[aoff + 64 * SAS] = rA1;
    // --- B convert + store: [m][k] bf16 pairs, XOR-swizzled chunks, 2-way banks ---
    {
      const float v0[8] = {rBa0.x, rBa0.y, rBa0.z, rBa0.w, rBa1.x, rBa1.y, rBa1.z, rBa1.w};
      const float v1[8] = {rBb0.x, rBb0.y, rBb0.z, rBb0.w, rBb1.x, rBb1.y, rBb1.z, rBb1.w};
#pragma unroll
      for (int e = 0; e < 8; e++) {
        ssq[e] += v0[e] * v0[e] + v1[e] * v1[e];
        const int m = m4 + (e & 3) + ((e >> 2) << 6);   // m4+e' or m4+64+e'
        const int fm = (m >> 3) & 3;
        const unsigned int pr = (unsigned int)f2bf(v0[e]) | ((unsigned int)f2bf(v1[e]) << 16);
        *(unsigned int*)&sB[m * SAS + ((gB ^ fm) << 3) + kin] = pr;
      }
    }
    // --- prefetch next K-step into registers (in flight across barriers + MFMA) ---
    {
      const int kn = k0 + 32;
      if (kn < C_) {
        rA0 = *(const short8*)(qA0 + kn);
        rA1 = *(const short8*)(qA1 + kn);
        const float* p0 = tbase + (size_t)kn * M_;
        const float* p1 = p0 + M_;
        rBa0 = *(const float4*)p0;  rBa1 = *(const float4*)(p0 + 64);
        rBb0 = *(const float4*)p1;  rBb1 = *(const float4*)(p1 + 64);
      }
    }
    __syncthreads();
    short8 af[4], bfr[4];
#pragma unroll
    for (int i = 0; i < 4; i++)
      af[i] = *(const short8*)&sA[(wn * 64 + i * 16 + ln) * SAS + (lg << 3)];
#pragma unroll
    for (int j = 0; j < 4; j++) {
      const int m = wm * 64 + j * 16 + ln;
      const int fm = (m >> 3) & 3;
      bfr[j] = *(const short8*)&sB[m * SAS + ((lg ^ fm) << 3)];
    }
#pragma unroll
    for (int i = 0; i < 4; i++)
#pragma unroll
      for (int j = 0; j < 4; j++)
        acc[i][j] = __builtin_amdgcn_mfma_f32_16x16x32_bf16(af[i], bfr[j], acc[i][j], 0, 0, 0);
    __syncthreads();
  }

  // --- column norms -> scale ---
  *(float4*)&ssqp[(t >> 4) * 128 + m4]      = make_float4(ssq[0], ssq[1], ssq[2], ssq[3]);
  *(float4*)&ssqp[(t >> 4) * 128 + m4 + 64] = make_float4(ssq[4], ssq[5], ssq[6], ssq[7]);
  __syncthreads();
  if (t < 128) {
    float s = 0.f;
#pragma unroll
    for (int g = 0; g < 16; g++) s += ssqp[g * 128 + t];
    scl[t] = 1.f / (fmaxf(sqrtf(s), EPS_) * TEMP_);
    // target keypoint geometry for n = t
    const float kx = kps_trg[((size_t)b * N_ + t) * 2 + 0];
    const float ky = kps_trg[((size_t)b * N_ + t) * 2 + 1];
    const float gx = kx * (1.f / 16.f), gy = ky * (1.f / 16.f);
    const int x0 = (int)fminf(fmaxf(floorf(gx), 0.f), 63.f);
    const int y0 = (int)fminf(fmaxf(floorf(gy), 0.f), 63.f);
    const int x1 = min(x0 + 1, 63), y1 = min(y0 + 1, 63);
    const float x0f = (float)x0, x1f = (float)x1, y0f = (float)y0, y1f = (float)y1;
    const float mk = (mask[(size_t)b * N_ + t] != 0) ? 1.f : 0.f;
    const int i0 = y0 * WF + x0, i1 = y1 * WF + x0;
    const int i2 = y0 * WF + x1, i3 = y1 * WF + x1;
    const float w0 = (x1f - gx) * (y1f - gy) * mk;
    const float w1 = (x1f - gx) * (gy - y0f) * mk;
    const float w2 = (gx - x0f) * (y1f - gy) * mk;
    const float w3 = (gx - x0f) * (gy - y0f) * mk;
    tidx[t][0] = i0; tw[t][0] = w0;
    tidx[t][1] = i1; tw[t][1] = w1;
    tidx[t][2] = i2; tw[t][2] = w2;
    tidx[t][3] = i3; tw[t][3] = w3;
    unsigned tm = 0u;
    if (w0 != 0.f) tm |= 1u << (i0 >> 7);
    if (w1 != 0.f) tm |= 1u << (i1 >> 7);
    if (w2 != 0.f) tm |= 1u << (i2 >> 7);
    if (w3 != 0.f) tm |= 1u << (i3 >> 7);
    tmask[t] = tm;
  }
  __syncthreads();

  float scj[4];
#pragma unroll
  for (int j = 0; j < 4; j++) scj[j] = scl[wm * 64 + j * 16 + ln];
#pragma unroll
  for (int i = 0; i < 4; i++)
#pragma unroll
    for (int j = 0; j < 4; j++) acc[i][j] *= scj[j];

  // --- per-row (max, sumexp) over this wave's 64 m, then target-logit extraction ---
  const unsigned mbbit = 1u << mb;
#pragma unroll
  for (int i = 0; i < 4; i++) {
#pragma unroll
    for (int r = 0; r < 4; r++) {
      float mx = fmaxf(fmaxf(acc[i][0][r], acc[i][1][r]), fmaxf(acc[i][2][r], acc[i][3][r]));
#pragma unroll
      for (int msk = 1; msk < 16; msk <<= 1) mx = fmaxf(mx, __shfl_xor(mx, msk, 64));
      float sm = __expf(acc[i][0][r] - mx) + __expf(acc[i][1][r] - mx) +
                 __expf(acc[i][2][r] - mx) + __expf(acc[i][3][r] - mx);
#pragma unroll
      for (int msk = 1; msk < 16; msk <<= 1) sm += __shfl_xor(sm, msk, 64);
      if (ln == 0) lser[(wn * 64 + i * 16 + lg * 4 + r) * 2 + wm] = make_float2(mx, sm);

      const int n = wn * 64 + i * 16 + lg * 4 + r;
      if (tmask[n] & mbbit) {           // skip dead compare loops: targets rarely in this chunk
        const int4  id4 = *(const int4*)&tidx[n][0];
        const float4 w4 = *(const float4*)&tw[n][0];
        const int   ida[4] = {id4.x, id4.y, id4.z, id4.w};
        const float wwa[4] = {w4.x, w4.y, w4.z, w4.w};
#pragma unroll
        for (int j = 0; j < 4; j++) {
          const int mg = m0 + wm * 64 + j * 16 + ln;
          const float lv = acc[i][j][r];
#pragma unroll
          for (int cc = 0; cc < 4; cc++)
            if (ida[cc] == mg && wwa[cc] != 0.f)
              atomicAdd(&tacc[(size_t)b * N_ + n], wwa[cc] * lv);
        }
      }
    }
  }
  __syncthreads();
  if (t < 128) {
    const float2 u = lser[t * 2 + 0], v = lser[t * 2 + 1];
    const float M = fmaxf(u.x, v.x);
    const float S = u.y * __expf(u.x - M) + v.y * __expf(v.x - M);
    part[((size_t)b * N_ + t) * NCH + mb] = make_float2(M, S);
  }
}

// ============ k4: per-(b,n) loss combine + masked-sum atomics ============
__global__ __launch_bounds__(128) void k4_comb(const float2* __restrict__ part,
                                               const float* __restrict__ tacc,
                                               const float* __restrict__ kps_trg,
                                               const int* __restrict__ mask,
                                               float* __restrict__ gs) {
  const int b = blockIdx.x, t = threadIdx.x;  // t = n
  const float2* p = part + ((size_t)b * N_ + t) * NCH;
  float M = -INFINITY;
#pragma unroll 8
  for (int c = 0; c < NCH; c++) M = fmaxf(M, p[c].x);
  float S = 0.f;
#pragma unroll 8
  for (int c = 0; c < NCH; c++) S += p[c].y * __expf(p[c].x - M);
  const float lse = M + logf(S);

  const float kx = kps_trg[((size_t)b * N_ + t) * 2 + 0];
  const float ky = kps_trg[((size_t)b * N_ + t) * 2 + 1];
  const float gx = kx * (1.f / 16.f), gy = ky * (1.f / 16.f);
  const int x0 = (int)fminf(fmaxf(floorf(gx), 0.f), 63.f);
  const int y0 = (int)fminf(fmaxf(floorf(gy), 0.f), 63.f);
  const int x1 = min(x0 + 1, 63), y1 = min(y0 + 1, 63);
  const float mk = (mask[(size_t)b * N_ + t] != 0) ? 1.f : 0.f;
  const float wsum = (float)(x1 - x0) * (float)(y1 - y0) * mk;

  float loss = wsum * lse - tacc[(size_t)b * N_ + t];
  float cnt = mk;
  loss = wave_sum(loss);
  cnt = wave_sum(cnt);
  __shared__ float sl[2], sc2[2];
  if ((t & 63) == 0) { sl[t >> 6] = loss; sc2[t >> 6] = cnt; }
  __syncthreads();
  if (t == 0) {
    atomicAdd(&gs[0], sl[0] + sl[1]);
    atomicAdd(&gs[1], sc2[0] + sc2[1]);
  }
}

__global__ void k5_final(const float* __restrict__ gs, float* __restrict__ out) {
  out[0] = gs[0] / fmaxf(gs[1], 1.f);
}

extern "C" void kernel_launch(void* const* d_in, const int* in_sizes, int n_in,
                              void* d_out, int out_size, void* d_ws, size_t ws_size,
                              hipStream_t stream) {
  const float* feats_src = (const float*)d_in[0];
  const float* feats_trg = (const float*)d_in[1];
  const float* kps_src   = (const float*)d_in[2];
  const float* kps_trg   = (const float*)d_in[3];
  const int*   kps_mask  = (const int*)d_in[4];
  float* out = (float*)d_out;

  // ws layout (bytes):
  //   0            ssqg   : B*N*4 floats          = 65536
  //   65536        tacc   : B*N floats            = 16384
  //   81920        gs     : 2 floats              = 8
  //   82432        corner : B*C*N*4 ushort        = 8388608
  //   8471040      qbf    : B*N*C ushort          = 2097152
  //   10568192     part   : B*N*NCH float2        = 1048576
  //   total ~11.6 MB
  char* wsb = (char*)d_ws;
  float*  ssqg   = (float*)(wsb + 0);
  float*  tacc   = (float*)(wsb + 65536);
  float*  gs     = (float*)(wsb + 81920);
  ushort* corner = (ushort*)(wsb + 82432);
  ushort* qbf    = (ushort*)(wsb + 8471040);
  float2* part   = (float2*)(wsb + 10568192);

  hipMemsetAsync(wsb, 0, 81928, stream);  // zero ssqg + tacc + gs

  k1a_stage<<<dim3(C_ / 2, B_), 256, 0, stream>>>(feats_src, kps_src, corner, ssqg);
  k1b2_combine<<<dim3(C_ / 32, B_), 256, 0, stream>>>(corner, ssqg, kps_src, qbf);
  k2_mfma<<<dim3(NCH, B_), 256, 0, stream>>>(feats_trg, qbf, kps_trg, kps_mask, part, tacc);
  k4_comb<<<dim3(B_), 128, 0, stream>>>(part, tacc, kps_trg, kps_mask, gs);
  k5_final<<<1, 1, 0, stream>>>(gs, out);
}